// Round 11
// baseline (909.411 us; speedup 1.0000x reference)
//
#include <hip/hip_runtime.h>
#include <hip/hip_bf16.h>
#include <cstdint>
#include <cstddef>

constexpr int F_IN = 64;
constexpr int HID  = 128;
constexpr int SCHUNK = 4096;   // edges per scatter block (16/thread)

typedef __attribute__((ext_vector_type(8))) short short8v;
typedef __attribute__((ext_vector_type(4))) float f32x4;
typedef __attribute__((ext_vector_type(8))) unsigned short ushort8v;

__device__ __forceinline__ float bf2f(unsigned short u) {
  return __uint_as_float((unsigned)u << 16);
}
__device__ __forceinline__ unsigned short f2bf(float x) {
  unsigned u = __float_as_uint(x);
  u += 0x7FFFu + ((u >> 16) & 1u);   // round-to-nearest-even
  return (unsigned short)(u >> 16);
}

// ================= CSR build via 1024-way bucketing =================
__global__ __launch_bounds__(256) void k_bhist(const int* __restrict__ ei,
                                               int* __restrict__ bcnt, int E) {
  __shared__ int hist[1024];
  int t = threadIdx.x;
  for (int k = t; k < 1024; k += 256) hist[k] = 0;
  __syncthreads();
  for (int i = blockIdx.x * 256 + t; i < E; i += gridDim.x * 256)
    atomicAdd(&hist[ei[E + i] >> 7], 1);
  __syncthreads();
  for (int k = t; k < 1024; k += 256)
    if (hist[k]) atomicAdd(&bcnt[k], hist[k]);
}

__global__ __launch_bounds__(1024) void k_bscan(const int* __restrict__ bcnt,
                                                int* __restrict__ boff,
                                                int* __restrict__ bcur, int nb) {
  __shared__ int tmp[1024];
  int t = threadIdx.x;
  int v = (t < nb) ? bcnt[t] : 0;
  tmp[t] = v;
  __syncthreads();
  #pragma unroll
  for (int off = 1; off < 1024; off <<= 1) {
    int x = tmp[t];
    int add = (t >= off) ? tmp[t - off] : 0;
    __syncthreads();
    tmp[t] = x + add;
    __syncthreads();
  }
  if (t < nb) {
    int ex = tmp[t] - v;
    boff[t] = ex;
    bcur[t] = ex;
    if (t == nb - 1) boff[nb] = tmp[t];
  }
}

__global__ __launch_bounds__(256) void k_bscat(const int* __restrict__ ei,
                                               int* __restrict__ bcur,
                                               uint2* __restrict__ pairs, int E) {
  __shared__ int lh[1024];
  __shared__ int lc[1024];
  int t = threadIdx.x;
  int start = blockIdx.x * SCHUNK;
  if (start >= E) return;
  int end = min(start + SCHUNK, E);
  for (int k = t; k < 1024; k += 256) { lh[k] = 0; lc[k] = 0; }
  __syncthreads();
  int dreg[SCHUNK / 256];
  #pragma unroll
  for (int q = 0; q < SCHUNK / 256; ++q) {
    int i = start + q * 256 + t;
    int d = (i < end) ? ei[E + i] : -1;
    dreg[q] = d;
    if (d >= 0) atomicAdd(&lh[d >> 7], 1);
  }
  __syncthreads();
  for (int k = t; k < 1024; k += 256) {
    int c = lh[k];
    lh[k] = (c > 0) ? atomicAdd(&bcur[k], c) : 0;
  }
  __syncthreads();
  #pragma unroll
  for (int q = 0; q < SCHUNK / 256; ++q) {
    int i = start + q * 256 + t;
    int d = dreg[q];
    if (d < 0) continue;
    int s = ei[i];
    int b = d >> 7;
    int loc = atomicAdd(&lc[b], 1);
    pairs[lh[b] + loc] = make_uint2((unsigned)s, (unsigned)d);
  }
}

// block per bucket: self-loop (first slot, deterministic) + pairs scatter.
__global__ __launch_bounds__(256) void k_bfin(const uint2* __restrict__ pairs,
                                              const int* __restrict__ boff,
                                              int* __restrict__ row_off,
                                              int* __restrict__ csr_src,
                                              int n, int E) {
  __shared__ int ldeg[128];
  __shared__ int lcur[128];
  int b = blockIdx.x;
  int t = threadIdx.x;
  int pb = boff[b], pe = boff[b + 1];
  int fullbase = pb + min(b << 7, n);
  int idx = (b << 7) + t;
  if (t < 128) ldeg[t] = (idx < n) ? 1 : 0;   // self-loop
  __syncthreads();
  for (int j = pb + t; j < pe; j += 256)
    atomicAdd(&ldeg[pairs[j].y & 127], 1);
  __syncthreads();
  int cnt = (t < 128) ? ldeg[t] : 0;
  for (int off = 1; off < 128; off <<= 1) {
    int add = (t < 128 && t >= off) ? ldeg[t - off] : 0;
    __syncthreads();
    if (t < 128) ldeg[t] += add;
    __syncthreads();
  }
  if (t < 128) {
    int base = fullbase + ldeg[t] - cnt;
    if (idx < n) {
      row_off[idx] = base;
      csr_src[base] = idx;        // self-loop first (deterministic slot)
      lcur[t] = base + 1;
    } else lcur[t] = base;
  }
  if (b == 0 && t == 255) row_off[n] = E + n;
  __syncthreads();
  for (int j = pb + t; j < pe; j += 256) {
    uint2 pr = pairs[j];
    int pos = atomicAdd(&lcur[pr.y & 127], 1);
    csr_src[pos] = (int)pr.x;
  }
}

// ---------------- fp32 -> bf16 convert (4-wide) ----------------
__global__ void k_tobf4(const float4* __restrict__ X, ushort4* __restrict__ Y,
                        int total4) {
  int i = blockIdx.x * 256 + threadIdx.x;
  if (i >= total4) return;
  float4 v = X[i];
  ushort4 o;
  o.x = f2bf(v.x); o.y = f2bf(v.y); o.z = f2bf(v.z); o.w = f2bf(v.w);
  Y[i] = o;
}

// ---- pack all three W into MFMA B-fragment order, bf16, one launch ----
__global__ void k_wpack3(const float* __restrict__ W1, const float* __restrict__ W2,
                         const float* __restrict__ W3, unsigned short* __restrict__ Wf1,
                         unsigned short* __restrict__ Wf2, unsigned short* __restrict__ Wf3) {
  int i = blockIdx.x * 256 + threadIdx.x;
  const float* W; unsigned short* Wf; int idx;
  if (i < 8192)       { W = W1; Wf = Wf1; idx = i; }
  else if (i < 24576) { W = W2; Wf = Wf2; idx = i - 8192; }
  else if (i < 40960) { W = W3; Wf = Wf3; idx = i - 24576; }
  else return;
  int j    = idx & 7;
  int lane = (idx >> 3) & 63;
  int t    = (idx >> 9) & 7;
  int ks   = idx >> 12;
  int k = ks * 32 + (lane >> 4) * 8 + j;
  int c = t * 16 + (lane & 15);
  Wf[idx] = f2bf(W[k * 128 + c]);
}

// ============ MFMA GEMM + fused alpha: [n,K] bf16 @ Wf ============
// Output in SLICED layout: Y[t][r][ln] = Y[t*n16 + r*16 + ln] (slice t = cols t*16..)
template<int K, int HEADS>
__global__ __launch_bounds__(256) void k_mgemm(const short* __restrict__ Xb,
                                               const short* __restrict__ Wf,
                                               const float* __restrict__ a_s,
                                               const float* __restrict__ a_d,
                                               unsigned short* __restrict__ Y,
                                               float* __restrict__ AS,
                                               float* __restrict__ AD, int n, int n16) {
  int wv   = threadIdx.x >> 6;
  int lane = threadIdx.x & 63;
  int r0   = blockIdx.x * 64 + wv * 16;
  int ln = lane & 15, kg = lane >> 4;
  f32x4 acc[8] = {};
  int arow = min(r0 + ln, n - 1);
  const short* aptr = Xb + arow * K + kg * 8;
  #pragma unroll
  for (int ks = 0; ks < K / 32; ++ks) {
    short8v a = *(const short8v*)(aptr + ks * 32);
    const short* wp = Wf + ks * 4096 + lane * 8;
    #pragma unroll
    for (int t = 0; t < 8; ++t) {
      short8v b = *(const short8v*)(wp + t * 512);
      acc[t] = __builtin_amdgcn_mfma_f32_16x16x32_bf16(a, b, acc[t], 0, 0, 0);
    }
  }
  float asv[8], adv[8];
  #pragma unroll
  for (int t = 0; t < 8; ++t) { asv[t] = a_s[t * 16 + ln]; adv[t] = a_d[t * 16 + ln]; }
  #pragma unroll
  for (int reg = 0; reg < 4; ++reg) {
    int r = r0 + kg * 4 + reg;
    bool valid = (r < n);
    if (HEADS == 1) {
      float s1 = 0.f, s2 = 0.f;
      #pragma unroll
      for (int t = 0; t < 8; ++t) {
        s1 = fmaf(acc[t][reg], asv[t], s1);
        s2 = fmaf(acc[t][reg], adv[t], s2);
      }
      #pragma unroll
      for (int off = 1; off < 16; off <<= 1) {
        s1 += __shfl_xor(s1, off);
        s2 += __shfl_xor(s2, off);
      }
      if (valid && ln == 0) { AS[r] = s1; AD[r] = s2; }
    } else {
      float s1[8], s2[8];
      #pragma unroll
      for (int t = 0; t < 8; ++t) {
        s1[t] = acc[t][reg] * asv[t];
        s2[t] = acc[t][reg] * adv[t];
      }
      #pragma unroll
      for (int off = 1; off < 16; off <<= 1) {
        #pragma unroll
        for (int t = 0; t < 8; ++t) {
          s1[t] += __shfl_xor(s1[t], off);
          s2[t] += __shfl_xor(s2[t], off);
        }
      }
      float w1 = s1[0], w2 = s2[0];
      #pragma unroll
      for (int t = 1; t < 8; ++t) {
        w1 = (ln == t) ? s1[t] : w1;
        w2 = (ln == t) ? s2[t] : w2;
      }
      if (valid && ln < 8) { AS[r * 8 + ln] = w1; AD[r * 8 + ln] = w2; }
    }
  }
  #pragma unroll
  for (int t = 0; t < 8; ++t) {
    #pragma unroll
    for (int reg = 0; reg < 4; ++reg) {
      int r = r0 + kg * 4 + reg;
      if (r < n) Y[t * n16 + r * 16 + ln] = f2bf(acc[t][reg]);
    }
  }
}

// ---- edge attention precompute, 1 head: 16 lanes per dst node ----
__global__ __launch_bounds__(256) void k_edgep1(const int* __restrict__ row_off,
    const int* __restrict__ csr_src, const float* __restrict__ AS,
    const float* __restrict__ AD, float* __restrict__ attn, int n) {
  int tid = blockIdx.x * 256 + threadIdx.x;
  int wid = tid >> 4;
  int ll  = threadIdx.x & 15;
  if (wid >= n) return;
  float adv = AD[wid];
  int jb = row_off[wid], je = row_off[wid + 1];
  float den = 0.f;
  for (int j = jb + ll; j < je; j += 16) {
    int s = csr_src[j];
    float e = AS[s] + adv;
    e = (e > 0.f) ? e : 0.2f * e;
    float p = __expf(e);
    attn[j] = p;
    den += p;
  }
  #pragma unroll
  for (int off = 1; off < 16; off <<= 1) den += __shfl_xor(den, off);
  float inv = 1.f / (den + 1e-16f);
  for (int j = jb + ll; j < je; j += 16) attn[j] *= inv;
}

// ---- edge attention precompute, 8 heads: 32 lanes per dst (4 edges x 8 heads)
// writes slice-major attn[h*AE + j]
__global__ __launch_bounds__(256) void k_edgep8(const int* __restrict__ row_off,
    const int* __restrict__ csr_src, const float* __restrict__ AS,
    const float* __restrict__ AD, float* __restrict__ attn, int AE, int n) {
  int tid = blockIdx.x * 256 + threadIdx.x;
  int wid = tid >> 5;
  int ll  = threadIdx.x & 31;
  if (wid >= n) return;
  int e = ll >> 3, h = ll & 7;
  float adv = AD[wid * 8 + h];
  int jb = row_off[wid], je = row_off[wid + 1];
  float den = 0.f;
  for (int j = jb + e; j < je; j += 4) {
    int s = csr_src[j];
    float x = AS[s * 8 + h] + adv;
    x = (x > 0.f) ? x : 0.2f * x;
    float p = __expf(x);
    attn[h * AE + j] = p;
    den += p;
  }
  den += __shfl_xor(den, 8);
  den += __shfl_xor(den, 16);
  float inv = 1.f / (den + 1e-16f);
  for (int j = jb + e; j < je; j += 4) attn[h * AE + j] *= inv;
}

// ---- SLICED aggregation: slice = blockIdx&7 (XCD-pinned; Hs slice 3.2MB
// ---- L2-resident). 2 lanes/node x 8ch (16B loads), 8-deep batching.
// ---- attn already normalized; writes T sliced bf16 (+bias).
__global__ __launch_bounds__(256) void k_aggs(const unsigned short* __restrict__ Hs,
    const int* __restrict__ row_off, const int* __restrict__ csr_src,
    const float* __restrict__ attn, int astride, const float* __restrict__ bias,
    unsigned short* __restrict__ T, int n, int n16) {
  int s   = blockIdx.x & 7;
  int grp = blockIdx.x >> 3;
  int lane = threadIdx.x & 63;
  int wave = threadIdx.x >> 6;
  int node = grp * 128 + wave * 32 + (lane >> 1);
  if (node >= n) return;
  int half = lane & 1;
  const unsigned short* Hsl = Hs + (size_t)s * n16;
  const float* at = attn + (size_t)s * astride;
  int jb = row_off[node], je = row_off[node + 1];
  float a[8] = {};
  int j = jb;
  for (; j + 8 <= je; j += 8) {
    int sk[8]; float wk[8]; ushort8v uu[8];
    #pragma unroll
    for (int q = 0; q < 8; ++q) sk[q] = __builtin_nontemporal_load(csr_src + j + q);
    #pragma unroll
    for (int q = 0; q < 8; ++q) uu[q] = *(const ushort8v*)(Hsl + (sk[q] << 4) + half * 8);
    #pragma unroll
    for (int q = 0; q < 8; ++q) wk[q] = __builtin_nontemporal_load(at + j + q);
    #pragma unroll
    for (int q = 0; q < 8; ++q) {
      #pragma unroll
      for (int m = 0; m < 8; ++m) a[m] = fmaf(wk[q], bf2f(uu[q][m]), a[m]);
    }
  }
  for (; j < je; ++j) {
    int sv = __builtin_nontemporal_load(csr_src + j);
    float w = __builtin_nontemporal_load(at + j);
    ushort8v u = *(const ushort8v*)(Hsl + (sv << 4) + half * 8);
    #pragma unroll
    for (int m = 0; m < 8; ++m) a[m] = fmaf(w, bf2f(u[m]), a[m]);
  }
  int cbase = s * 16 + half * 8;
  ushort8v ob;
  #pragma unroll
  for (int m = 0; m < 8; ++m) ob[m] = f2bf(a[m] + bias[cbase + m]);
  *(ushort8v*)(T + (size_t)s * n16 + node * 16 + half * 8) = ob;
}

// ---- post: ELU + LN + residual. 16 lanes/node; reads sliced T, writes row-major F
__global__ __launch_bounds__(256) void k_post(const unsigned short* __restrict__ T,
    const unsigned short* __restrict__ RES, const float* __restrict__ gamma,
    const float* __restrict__ beta, unsigned short* __restrict__ F,
    int n, int n16, int has_res) {
  int tid = blockIdx.x * 256 + threadIdx.x;
  int node = tid >> 4;
  int ll = threadIdx.x & 15;
  if (node >= n) return;
  int sl = ll >> 1, half = ll & 1;
  ushort8v tv = *(const ushort8v*)(T + (size_t)sl * n16 + node * 16 + half * 8);
  float e[8];
  float s1 = 0.f, s2 = 0.f;
  #pragma unroll
  for (int m = 0; m < 8; ++m) {
    float t = bf2f(tv[m]);
    t = t > 0.f ? t : __expf(t) - 1.f;
    e[m] = t; s1 += t; s2 += t * t;
  }
  #pragma unroll
  for (int off = 1; off < 16; off <<= 1) {
    s1 += __shfl_xor(s1, off);
    s2 += __shfl_xor(s2, off);
  }
  float mu  = s1 * (1.f / 128.f);
  float var = s2 * (1.f / 128.f) - mu * mu;
  float rs  = rsqrtf(var + 1e-5f);
  int c = ll * 8;                           // == sl*16 + half*8
  float4 gv0 = *(const float4*)(gamma + c);
  float4 gv1 = *(const float4*)(gamma + c + 4);
  float4 bv0 = *(const float4*)(beta + c);
  float4 bv1 = *(const float4*)(beta + c + 4);
  float gg[8] = {gv0.x, gv0.y, gv0.z, gv0.w, gv1.x, gv1.y, gv1.z, gv1.w};
  float bb[8] = {bv0.x, bv0.y, bv0.z, bv0.w, bv1.x, bv1.y, bv1.z, bv1.w};
  float rr[8] = {};
  if (has_res) {
    ushort8v rv = *(const ushort8v*)(RES + (size_t)node * 128 + c);
    #pragma unroll
    for (int m = 0; m < 8; ++m) rr[m] = bf2f(rv[m]);
  }
  ushort8v ob;
  #pragma unroll
  for (int m = 0; m < 8; ++m) ob[m] = f2bf((e[m] - mu) * rs * gg[m] + bb[m] + rr[m]);
  *(ushort8v*)(F + (size_t)node * 128 + c) = ob;
}

// ---- fused head: block per graph: mean-pool -> MLP1+ELU -> MLP2 ----
__global__ __launch_bounds__(128) void k_head(const unsigned short* __restrict__ Hf,
    const int* __restrict__ batch, const float* __restrict__ lw1,
    const float* __restrict__ lb1, const float* __restrict__ lw2,
    const float* __restrict__ lb2, float* __restrict__ out, int n) {
  __shared__ float pooled[128];
  __shared__ float h1[128];
  int g = blockIdx.x;
  int c = threadIdx.x;
  int lo = 0, hi = n;
  while (lo < hi) { int mid = (lo + hi) >> 1; if (batch[mid] < g) lo = mid + 1; else hi = mid; }
  int start = lo;
  hi = n;
  while (lo < hi) { int mid = (lo + hi) >> 1; if (batch[mid] < g + 1) lo = mid + 1; else hi = mid; }
  int end = lo;
  float s = 0.f;
  for (int i = start; i < end; ++i) s += bf2f(Hf[(size_t)i * 128 + c]);
  pooled[c] = s / (float)max(end - start, 1);
  __syncthreads();
  float acc = lb1[c];
  #pragma unroll 8
  for (int k = 0; k < 128; ++k) acc = fmaf(pooled[k], lw1[k * 128 + c], acc);
  h1[c] = acc > 0.f ? acc : __expf(acc) - 1.f;
  __syncthreads();
  float acc2 = lb2[c];
  #pragma unroll 8
  for (int k = 0; k < 128; ++k) acc2 = fmaf(h1[k], lw2[k * 128 + c], acc2);
  out[(size_t)g * 128 + c] = acc2;
}

extern "C" void kernel_launch(void* const* d_in, const int* in_sizes, int n_in,
                              void* d_out, int out_size, void* d_ws, size_t ws_size,
                              hipStream_t stream) {
  const float* x   = (const float*)d_in[0];
  const int*   ei  = (const int*)d_in[1];
  const int*   bat = (const int*)d_in[2];
  const float* W1  = (const float*)d_in[3];
  const float* as1 = (const float*)d_in[4];
  const float* ad1 = (const float*)d_in[5];
  const float* b1  = (const float*)d_in[6];
  const float* W2  = (const float*)d_in[7];
  const float* as2 = (const float*)d_in[8];
  const float* ad2 = (const float*)d_in[9];
  const float* b2  = (const float*)d_in[10];
  const float* W3  = (const float*)d_in[11];
  const float* as3 = (const float*)d_in[12];
  const float* ad3 = (const float*)d_in[13];
  const float* b3  = (const float*)d_in[14];
  const float* g1  = (const float*)d_in[15];
  const float* be1 = (const float*)d_in[16];
  const float* g2  = (const float*)d_in[17];
  const float* be2 = (const float*)d_in[18];
  const float* g3  = (const float*)d_in[19];
  const float* be3 = (const float*)d_in[20];
  const float* lw1 = (const float*)d_in[21];
  const float* lb1 = (const float*)d_in[22];
  const float* lw2 = (const float*)d_in[23];
  const float* lb2 = (const float*)d_in[24];

  int N = in_sizes[0] / F_IN;
  int E = in_sizes[1] / 2;
  int G = out_size / HID;
  int tot = E + N;                    // edges incl self-loops
  int nb  = (N + 127) >> 7;           // buckets (<=1024)
  int n16 = N * 16;

  char* p = (char*)d_ws;
  auto alloc = [&](size_t bytes) { char* r = p; p += (bytes + 511) & ~(size_t)511; return r; };
  int*   bcnt    = (int*)  alloc(1024 * 4);
  int*   boff    = (int*)  alloc(1025 * 4);
  int*   bcur    = (int*)  alloc(1024 * 4);
  int*   row_off = (int*)  alloc((size_t)(N + 1) * 4);
  int*   csr_src = (int*)  alloc((size_t)tot * 4);
  uint2* pairs   = (uint2*)alloc((size_t)E * 8);      // dead after k_bfin
  float* AS      = (float*)alloc((size_t)N * 8 * 4);
  float* AD      = (float*)alloc((size_t)N * 8 * 4);
  float* attn    = (float*)alloc((size_t)tot * 8 * 4);   // [8][E+N] slice-major (L1) / [E+N] (L2,3)
  unsigned short* Hs  = (unsigned short*)alloc((size_t)N * HID * 2);   // sliced [8][N][16]
  unsigned short* T   = (unsigned short*)alloc((size_t)N * HID * 2);   // sliced agg out
  unsigned short* Fb0 = (unsigned short*)alloc((size_t)N * HID * 2);
  unsigned short* Fb1 = (unsigned short*)alloc((size_t)N * HID * 2);
  unsigned short* Fb2 = (unsigned short*)alloc((size_t)N * HID * 2);
  unsigned short* Wf1 = (unsigned short*)alloc(64 * 128 * 2);
  unsigned short* Wf2 = (unsigned short*)alloc(128 * 128 * 2);
  unsigned short* Wf3 = (unsigned short*)alloc(128 * 128 * 2);
  unsigned short* xb  = (unsigned short*)pairs;       // alias dead pairs buffer

  (void)hipMemsetAsync(bcnt, 0, 1024 * 4, stream);

  int sb = (E + SCHUNK - 1) / SCHUNK;
  k_bhist<<<256, 256, 0, stream>>>(ei, bcnt, E);
  k_bscan<<<1, 1024, 0, stream>>>(bcnt, boff, bcur, nb);
  k_bscat<<<sb, 256, 0, stream>>>(ei, bcur, pairs, E);
  k_bfin <<<nb, 256, 0, stream>>>(pairs, boff, row_off, csr_src, N, E);

  k_tobf4 <<<(N * F_IN / 4 + 255) / 256, 256, 0, stream>>>((const float4*)x,
                                                           (ushort4*)xb, N * F_IN / 4);
  k_wpack3<<<160, 256, 0, stream>>>(W1, W2, W3, Wf1, Wf2, Wf3);

  int mb  = (N + 63) / 64;                 // MFMA GEMM blocks
  int ep1 = (N * 16 + 255) / 256;          // edgep1 / post grids
  int ep8 = (N * 32 + 255) / 256;          // edgep8 grid
  int ags = 8 * ((N + 127) / 128);         // sliced agg grid (slice = bid&7)

  // ---- layer 1 (8 heads; slice == head)
  k_mgemm<64, 8><<<mb, 256, 0, stream>>>((const short*)xb, (const short*)Wf1,
                                         as1, ad1, Hs, AS, AD, N, n16);
  k_edgep8<<<ep8, 256, 0, stream>>>(row_off, csr_src, AS, AD, attn, tot, N);
  k_aggs  <<<ags, 256, 0, stream>>>(Hs, row_off, csr_src, attn, tot, b1, T, N, n16);
  k_post  <<<ep1, 256, 0, stream>>>(T, nullptr, g1, be1, Fb0, N, n16, 0);

  // ---- layer 2
  k_mgemm<128, 1><<<mb, 256, 0, stream>>>((const short*)Fb0, (const short*)Wf2,
                                          as2, ad2, Hs, AS, AD, N, n16);
  k_edgep1<<<ep1, 256, 0, stream>>>(row_off, csr_src, AS, AD, attn, N);
  k_aggs  <<<ags, 256, 0, stream>>>(Hs, row_off, csr_src, attn, 0, b2, T, N, n16);
  k_post  <<<ep1, 256, 0, stream>>>(T, Fb0, g2, be2, Fb1, N, n16, 1);

  // ---- layer 3
  k_mgemm<128, 1><<<mb, 256, 0, stream>>>((const short*)Fb1, (const short*)Wf3,
                                          as3, ad3, Hs, AS, AD, N, n16);
  k_edgep1<<<ep1, 256, 0, stream>>>(row_off, csr_src, AS, AD, attn, N);
  k_aggs  <<<ags, 256, 0, stream>>>(Hs, row_off, csr_src, attn, 0, b3, T, N, n16);
  k_post  <<<ep1, 256, 0, stream>>>(T, Fb1, g3, be3, Fb2, N, n16, 1);

  // ---- fused pool + MLP head
  k_head<<<G, 128, 0, stream>>>(Fb2, bat, lw1, lb1, lw2, lb2, (float*)d_out, N);
}

// Round 12
// 392.753 us; speedup vs baseline: 2.3155x; 2.3155x over previous
//
#include <hip/hip_runtime.h>
#include <hip/hip_bf16.h>
#include <cstdint>
#include <cstddef>

constexpr int F_IN = 64;
constexpr int HID  = 128;
constexpr int SCHUNK  = 4096;   // edges per scatter block (16/thread)
constexpr int BSTRIDE = 4096;   // pairs slots per bucket (mean 2046 + 45 sigma)

typedef __attribute__((ext_vector_type(8))) short short8v;
typedef __attribute__((ext_vector_type(4))) float f32x4;
typedef __attribute__((ext_vector_type(8))) unsigned short ushort8v;

__device__ __forceinline__ float bf2f(unsigned short u) {
  return __uint_as_float((unsigned)u << 16);
}
__device__ __forceinline__ unsigned short f2bf(float x) {
  unsigned u = __float_as_uint(x);
  u += 0x7FFFu + ((u >> 16) & 1u);   // round-to-nearest-even
  return (unsigned short)(u >> 16);
}

// ================= CSR build: direct strided scatter (no histogram) =========
__global__ __launch_bounds__(1024) void k_binit(int* __restrict__ bcur) {
  bcur[threadIdx.x] = threadIdx.x * BSTRIDE;
}

// block-aggregated scatter into fixed-stride bucket regions
__global__ __launch_bounds__(256) void k_bscat(const int* __restrict__ ei,
                                               int* __restrict__ bcur,
                                               uint2* __restrict__ pairs, int E) {
  __shared__ int lh[1024];
  __shared__ int lc[1024];
  int t = threadIdx.x;
  int start = blockIdx.x * SCHUNK;
  if (start >= E) return;
  int end = min(start + SCHUNK, E);
  for (int k = t; k < 1024; k += 256) { lh[k] = 0; lc[k] = 0; }
  __syncthreads();
  int dreg[SCHUNK / 256];
  #pragma unroll
  for (int q = 0; q < SCHUNK / 256; ++q) {
    int i = start + q * 256 + t;
    int d = (i < end) ? ei[E + i] : -1;
    dreg[q] = d;
    if (d >= 0) atomicAdd(&lh[d >> 7], 1);
  }
  __syncthreads();
  for (int k = t; k < 1024; k += 256) {
    int c = lh[k];
    lh[k] = (c > 0) ? atomicAdd(&bcur[k], c) : 0;
  }
  __syncthreads();
  #pragma unroll
  for (int q = 0; q < SCHUNK / 256; ++q) {
    int i = start + q * 256 + t;
    int d = dreg[q];
    if (d < 0) continue;
    int s = ei[i];
    int b = d >> 7;
    int loc = atomicAdd(&lc[b], 1);
    pairs[lh[b] + loc] = make_uint2((unsigned)s, (unsigned)d);
  }
}

// single block: counts from final cursors -> exclusive scan -> boff
__global__ __launch_bounds__(1024) void k_bcscan(const int* __restrict__ bcur,
                                                 int* __restrict__ boff, int nb) {
  __shared__ int tmp[1024];
  int t = threadIdx.x;
  int v = (t < nb) ? (bcur[t] - t * BSTRIDE) : 0;
  tmp[t] = v;
  __syncthreads();
  #pragma unroll
  for (int off = 1; off < 1024; off <<= 1) {
    int x = tmp[t];
    int add = (t >= off) ? tmp[t - off] : 0;
    __syncthreads();
    tmp[t] = x + add;
    __syncthreads();
  }
  if (t < nb) {
    boff[t] = tmp[t] - v;
    if (t == nb - 1) boff[nb] = tmp[t];
  }
}

// block per bucket: self-loop first slot (deterministic) + pairs scatter.
__global__ __launch_bounds__(256) void k_bfin(const uint2* __restrict__ pairs,
                                              const int* __restrict__ bcur,
                                              const int* __restrict__ boff,
                                              int* __restrict__ row_off,
                                              int* __restrict__ csr_src,
                                              int n, int E) {
  __shared__ int ldeg[128];
  __shared__ int lcur[128];
  int b = blockIdx.x;
  int t = threadIdx.x;
  int pb = b * BSTRIDE, pe = bcur[b];
  int fullbase = boff[b] + min(b << 7, n);
  int idx = (b << 7) + t;
  if (t < 128) ldeg[t] = (idx < n) ? 1 : 0;   // self-loop
  __syncthreads();
  for (int j = pb + t; j < pe; j += 256)
    atomicAdd(&ldeg[pairs[j].y & 127], 1);
  __syncthreads();
  int cnt = (t < 128) ? ldeg[t] : 0;
  for (int off = 1; off < 128; off <<= 1) {
    int add = (t < 128 && t >= off) ? ldeg[t - off] : 0;
    __syncthreads();
    if (t < 128) ldeg[t] += add;
    __syncthreads();
  }
  if (t < 128) {
    int base = fullbase + ldeg[t] - cnt;
    if (idx < n) {
      row_off[idx] = base;
      csr_src[base] = idx;        // self-loop first (deterministic slot)
      lcur[t] = base + 1;
    } else lcur[t] = base;
  }
  if (b == 0 && t == 255) row_off[n] = E + n;
  __syncthreads();
  for (int j = pb + t; j < pe; j += 256) {
    uint2 pr = pairs[j];
    int pos = atomicAdd(&lcur[pr.y & 127], 1);
    csr_src[pos] = (int)pr.x;
  }
}

// ---------------- fp32 -> bf16 convert (4-wide) ----------------
__global__ void k_tobf4(const float4* __restrict__ X, ushort4* __restrict__ Y,
                        int total4) {
  int i = blockIdx.x * 256 + threadIdx.x;
  if (i >= total4) return;
  float4 v = X[i];
  ushort4 o;
  o.x = f2bf(v.x); o.y = f2bf(v.y); o.z = f2bf(v.z); o.w = f2bf(v.w);
  Y[i] = o;
}

// ---- pack all three W into MFMA B-fragment order, bf16, one launch ----
__global__ void k_wpack3(const float* __restrict__ W1, const float* __restrict__ W2,
                         const float* __restrict__ W3, unsigned short* __restrict__ Wf1,
                         unsigned short* __restrict__ Wf2, unsigned short* __restrict__ Wf3) {
  int i = blockIdx.x * 256 + threadIdx.x;
  const float* W; unsigned short* Wf; int idx;
  if (i < 8192)       { W = W1; Wf = Wf1; idx = i; }
  else if (i < 24576) { W = W2; Wf = Wf2; idx = i - 8192; }
  else if (i < 40960) { W = W3; Wf = Wf3; idx = i - 24576; }
  else return;
  int j    = idx & 7;
  int lane = (idx >> 3) & 63;
  int t    = (idx >> 9) & 7;
  int ks   = idx >> 12;
  int k = ks * 32 + (lane >> 4) * 8 + j;
  int c = t * 16 + (lane & 15);
  Wf[idx] = f2bf(W[k * 128 + c]);
}

// ============ MFMA GEMM + fused alpha: [n,K] bf16 @ Wf -> Hb bf16, AS, AD ===
template<int K, int HEADS>
__global__ __launch_bounds__(256) void k_mgemm(const short* __restrict__ Xb,
                                               const short* __restrict__ Wf,
                                               const float* __restrict__ a_s,
                                               const float* __restrict__ a_d,
                                               unsigned short* __restrict__ Y,
                                               float* __restrict__ AS,
                                               float* __restrict__ AD, int n) {
  int wv   = threadIdx.x >> 6;
  int lane = threadIdx.x & 63;
  int r0   = blockIdx.x * 64 + wv * 16;
  int ln = lane & 15, kg = lane >> 4;
  f32x4 acc[8] = {};
  int arow = min(r0 + ln, n - 1);
  const short* aptr = Xb + arow * K + kg * 8;
  #pragma unroll
  for (int ks = 0; ks < K / 32; ++ks) {
    short8v a = *(const short8v*)(aptr + ks * 32);
    const short* wp = Wf + ks * 4096 + lane * 8;
    #pragma unroll
    for (int t = 0; t < 8; ++t) {
      short8v b = *(const short8v*)(wp + t * 512);
      acc[t] = __builtin_amdgcn_mfma_f32_16x16x32_bf16(a, b, acc[t], 0, 0, 0);
    }
  }
  float asv[8], adv[8];
  #pragma unroll
  for (int t = 0; t < 8; ++t) { asv[t] = a_s[t * 16 + ln]; adv[t] = a_d[t * 16 + ln]; }
  #pragma unroll
  for (int reg = 0; reg < 4; ++reg) {
    int r = r0 + kg * 4 + reg;
    bool valid = (r < n);
    if (HEADS == 1) {
      float s1 = 0.f, s2 = 0.f;
      #pragma unroll
      for (int t = 0; t < 8; ++t) {
        s1 = fmaf(acc[t][reg], asv[t], s1);
        s2 = fmaf(acc[t][reg], adv[t], s2);
      }
      #pragma unroll
      for (int off = 1; off < 16; off <<= 1) {
        s1 += __shfl_xor(s1, off);
        s2 += __shfl_xor(s2, off);
      }
      if (valid && ln == 0) { AS[r] = s1; AD[r] = s2; }
    } else {
      float s1[8], s2[8];
      #pragma unroll
      for (int t = 0; t < 8; ++t) {
        s1[t] = acc[t][reg] * asv[t];
        s2[t] = acc[t][reg] * adv[t];
      }
      #pragma unroll
      for (int off = 1; off < 16; off <<= 1) {
        #pragma unroll
        for (int t = 0; t < 8; ++t) {
          s1[t] += __shfl_xor(s1[t], off);
          s2[t] += __shfl_xor(s2[t], off);
        }
      }
      float w1 = s1[0], w2 = s2[0];
      #pragma unroll
      for (int t = 1; t < 8; ++t) {
        w1 = (ln == t) ? s1[t] : w1;
        w2 = (ln == t) ? s2[t] : w2;
      }
      if (valid && ln < 8) { AS[r * 8 + ln] = w1; AD[r * 8 + ln] = w2; }
    }
  }
  #pragma unroll
  for (int t = 0; t < 8; ++t) {
    #pragma unroll
    for (int reg = 0; reg < 4; ++reg) {
      int r = r0 + kg * 4 + reg;
      if (r < n) Y[r * 128 + t * 16 + ln] = f2bf(acc[t][reg]);
    }
  }
}

// ---- GAT aggregation: HALF-WAVE per dst, 4 ch/lane, cooperative no-max
// ---- softmax, deep load batching; + bias + ELU + LN + residual; bf16 I/O
template<int LOGC>
__global__ __launch_bounds__(256) void k_agg_post(const unsigned short* __restrict__ Hu,
    const int* __restrict__ row_off, const int* __restrict__ csr_src,
    const float* __restrict__ AS, const float* __restrict__ AD,
    const float* __restrict__ bias, const unsigned short* __restrict__ RES,
    const float* __restrict__ gamma, const float* __restrict__ beta,
    unsigned short* __restrict__ Yb, int n, int has_res) {
  int tid = blockIdx.x * 256 + threadIdx.x;
  int wid = tid >> 5;                      // half-wave (32 lanes) per node
  int ll  = threadIdx.x & 31;
  if (wid >= n) return;
  constexpr int NH  = HID >> LOGC;
  constexpr int SEG = (LOGC >= 7) ? 32 : (1 << (LOGC - 2));
  int abslane = threadIdx.x & 63;
  int c = ll << 2;
  int h = c >> LOGC;
  int r = ll & (SEG - 1);
  int sbase = abslane & ~(SEG - 1);
  float adv = AD[wid * NH + h];
  int jb = row_off[wid], je = row_off[wid + 1];
  float den = 0.f, a0 = 0.f, a1 = 0.f, a2 = 0.f, a3 = 0.f;
  for (int j0 = jb; j0 < je; j0 += SEG) {
    int cnt = min(SEG, je - j0);
    int s_l = 0; float p_l = 0.f;
    if (r < cnt) {
      s_l = csr_src[j0 + r];
      float e = AS[s_l * NH + h] + adv;
      e = (e > 0.f) ? e : 0.2f * e;
      p_l = __expf(e);
    }
    int k = 0;
    if (LOGC >= 7) {
      for (; k + 8 <= cnt; k += 8) {       // 8-deep: 8 loads in flight
        int   sk[8]; float pk[8]; ushort4 uu[8];
        #pragma unroll
        for (int q = 0; q < 8; ++q) sk[q] = __shfl(s_l, sbase | (k + q));
        #pragma unroll
        for (int q = 0; q < 8; ++q) uu[q] = *(const ushort4*)(Hu + (sk[q] << 7) + c);
        #pragma unroll
        for (int q = 0; q < 8; ++q) pk[q] = __shfl(p_l, sbase | (k + q));
        #pragma unroll
        for (int q = 0; q < 8; ++q) {
          den += pk[q];
          a0 = fmaf(pk[q], bf2f(uu[q].x), a0);
          a1 = fmaf(pk[q], bf2f(uu[q].y), a1);
          a2 = fmaf(pk[q], bf2f(uu[q].z), a2);
          a3 = fmaf(pk[q], bf2f(uu[q].w), a3);
        }
      }
    }
    for (; k + 4 <= cnt; k += 4) {
      int sk0 = __shfl(s_l, sbase | k);
      int sk1 = __shfl(s_l, sbase | (k + 1));
      int sk2 = __shfl(s_l, sbase | (k + 2));
      int sk3 = __shfl(s_l, sbase | (k + 3));
      ushort4 u0 = *(const ushort4*)(Hu + (sk0 << 7) + c);
      ushort4 u1 = *(const ushort4*)(Hu + (sk1 << 7) + c);
      ushort4 u2 = *(const ushort4*)(Hu + (sk2 << 7) + c);
      ushort4 u3 = *(const ushort4*)(Hu + (sk3 << 7) + c);
      float p0 = __shfl(p_l, sbase | k);
      float p1 = __shfl(p_l, sbase | (k + 1));
      float p2 = __shfl(p_l, sbase | (k + 2));
      float p3 = __shfl(p_l, sbase | (k + 3));
      den += (p0 + p1) + (p2 + p3);
      a0 = fmaf(p0, bf2f(u0.x), a0); a1 = fmaf(p0, bf2f(u0.y), a1);
      a2 = fmaf(p0, bf2f(u0.z), a2); a3 = fmaf(p0, bf2f(u0.w), a3);
      a0 = fmaf(p1, bf2f(u1.x), a0); a1 = fmaf(p1, bf2f(u1.y), a1);
      a2 = fmaf(p1, bf2f(u1.z), a2); a3 = fmaf(p1, bf2f(u1.w), a3);
      a0 = fmaf(p2, bf2f(u2.x), a0); a1 = fmaf(p2, bf2f(u2.y), a1);
      a2 = fmaf(p2, bf2f(u2.z), a2); a3 = fmaf(p2, bf2f(u2.w), a3);
      a0 = fmaf(p3, bf2f(u3.x), a0); a1 = fmaf(p3, bf2f(u3.y), a1);
      a2 = fmaf(p3, bf2f(u3.z), a2); a3 = fmaf(p3, bf2f(u3.w), a3);
    }
    for (; k < cnt; ++k) {
      int   s  = __shfl(s_l, sbase | k);
      float pk = __shfl(p_l, sbase | k);
      ushort4 u = *(const ushort4*)(Hu + (s << 7) + c);
      den += pk;
      a0 = fmaf(pk, bf2f(u.x), a0); a1 = fmaf(pk, bf2f(u.y), a1);
      a2 = fmaf(pk, bf2f(u.z), a2); a3 = fmaf(pk, bf2f(u.w), a3);
    }
  }
  float inv = 1.f / (den + 1e-16f);
  float4 bv = *(const float4*)(bias + c);
  float t0 = a0 * inv + bv.x;
  float t1 = a1 * inv + bv.y;
  float t2 = a2 * inv + bv.z;
  float t3 = a3 * inv + bv.w;
  float e0 = t0 > 0.f ? t0 : __expf(t0) - 1.f;
  float e1 = t1 > 0.f ? t1 : __expf(t1) - 1.f;
  float e2 = t2 > 0.f ? t2 : __expf(t2) - 1.f;
  float e3 = t3 > 0.f ? t3 : __expf(t3) - 1.f;
  float s1 = (e0 + e1) + (e2 + e3);
  float s2 = (e0 * e0 + e1 * e1) + (e2 * e2 + e3 * e3);
  #pragma unroll
  for (int off = 16; off >= 1; off >>= 1) {
    s1 += __shfl_xor(s1, off);
    s2 += __shfl_xor(s2, off);
  }
  float mu  = s1 * (1.f / 128.f);
  float var = s2 * (1.f / 128.f) - mu * mu;
  float rs  = rsqrtf(var + 1e-5f);
  int base = wid * HID;
  float r0 = 0.f, r1 = 0.f, r2 = 0.f, r3 = 0.f;
  if (has_res) {
    ushort4 rv = *(const ushort4*)(RES + base + c);
    r0 = bf2f(rv.x); r1 = bf2f(rv.y); r2 = bf2f(rv.z); r3 = bf2f(rv.w);
  }
  float4 gv = *(const float4*)(gamma + c);
  float4 betv = *(const float4*)(beta + c);
  ushort4 ob;
  ob.x = f2bf((e0 - mu) * rs * gv.x + betv.x + r0);
  ob.y = f2bf((e1 - mu) * rs * gv.y + betv.y + r1);
  ob.z = f2bf((e2 - mu) * rs * gv.z + betv.z + r2);
  ob.w = f2bf((e3 - mu) * rs * gv.w + betv.w + r3);
  *(ushort4*)(Yb + base + c) = ob;
}

// ---- fused head: block per graph: mean-pool -> MLP1+ELU -> MLP2 ----
__global__ __launch_bounds__(128) void k_head(const unsigned short* __restrict__ Hf,
    const int* __restrict__ batch, const float* __restrict__ lw1,
    const float* __restrict__ lb1, const float* __restrict__ lw2,
    const float* __restrict__ lb2, float* __restrict__ out, int n) {
  __shared__ float pooled[128];
  __shared__ float h1[128];
  int g = blockIdx.x;
  int c = threadIdx.x;
  int lo = 0, hi = n;
  while (lo < hi) { int mid = (lo + hi) >> 1; if (batch[mid] < g) lo = mid + 1; else hi = mid; }
  int start = lo;
  hi = n;
  while (lo < hi) { int mid = (lo + hi) >> 1; if (batch[mid] < g + 1) lo = mid + 1; else hi = mid; }
  int end = lo;
  float s = 0.f;
  for (int i = start; i < end; ++i) s += bf2f(Hf[(size_t)i * 128 + c]);
  pooled[c] = s / (float)max(end - start, 1);
  __syncthreads();
  float acc = lb1[c];
  #pragma unroll 8
  for (int k = 0; k < 128; ++k) acc = fmaf(pooled[k], lw1[k * 128 + c], acc);
  h1[c] = acc > 0.f ? acc : __expf(acc) - 1.f;
  __syncthreads();
  float acc2 = lb2[c];
  #pragma unroll 8
  for (int k = 0; k < 128; ++k) acc2 = fmaf(h1[k], lw2[k * 128 + c], acc2);
  out[(size_t)g * 128 + c] = acc2;
}

extern "C" void kernel_launch(void* const* d_in, const int* in_sizes, int n_in,
                              void* d_out, int out_size, void* d_ws, size_t ws_size,
                              hipStream_t stream) {
  const float* x   = (const float*)d_in[0];
  const int*   ei  = (const int*)d_in[1];
  const int*   bat = (const int*)d_in[2];
  const float* W1  = (const float*)d_in[3];
  const float* as1 = (const float*)d_in[4];
  const float* ad1 = (const float*)d_in[5];
  const float* b1  = (const float*)d_in[6];
  const float* W2  = (const float*)d_in[7];
  const float* as2 = (const float*)d_in[8];
  const float* ad2 = (const float*)d_in[9];
  const float* b2  = (const float*)d_in[10];
  const float* W3  = (const float*)d_in[11];
  const float* as3 = (const float*)d_in[12];
  const float* ad3 = (const float*)d_in[13];
  const float* b3  = (const float*)d_in[14];
  const float* g1  = (const float*)d_in[15];
  const float* be1 = (const float*)d_in[16];
  const float* g2  = (const float*)d_in[17];
  const float* be2 = (const float*)d_in[18];
  const float* g3  = (const float*)d_in[19];
  const float* be3 = (const float*)d_in[20];
  const float* lw1 = (const float*)d_in[21];
  const float* lb1 = (const float*)d_in[22];
  const float* lw2 = (const float*)d_in[23];
  const float* lb2 = (const float*)d_in[24];

  int N = in_sizes[0] / F_IN;
  int E = in_sizes[1] / 2;
  int G = out_size / HID;
  int tot = E + N;
  int nb  = (N + 127) >> 7;          // buckets (<=1024)

  char* p = (char*)d_ws;
  auto alloc = [&](size_t bytes) { char* r = p; p += (bytes + 511) & ~(size_t)511; return r; };
  int*   bcur    = (int*)  alloc(1024 * 4);
  int*   boff    = (int*)  alloc(1025 * 4);
  int*   row_off = (int*)  alloc((size_t)(N + 1) * 4);
  int*   csr_src = (int*)  alloc((size_t)tot * 4);
  uint2* pairs   = (uint2*)alloc((size_t)1024 * BSTRIDE * 8);  // dead after k_bfin
  float* AS      = (float*)alloc((size_t)N * 8 * 4);
  float* AD      = (float*)alloc((size_t)N * 8 * 4);
  unsigned short* Hb  = (unsigned short*)alloc((size_t)N * HID * 2);
  unsigned short* Fb0 = (unsigned short*)alloc((size_t)N * HID * 2);
  unsigned short* Fb1 = (unsigned short*)alloc((size_t)N * HID * 2);
  unsigned short* Fb2 = (unsigned short*)alloc((size_t)N * HID * 2);
  unsigned short* Wf1 = (unsigned short*)alloc(64 * 128 * 2);
  unsigned short* Wf2 = (unsigned short*)alloc(128 * 128 * 2);
  unsigned short* Wf3 = (unsigned short*)alloc(128 * 128 * 2);
  unsigned short* xb  = (unsigned short*)pairs;       // alias dead pairs buffer

  int sb = (E + SCHUNK - 1) / SCHUNK;
  k_binit <<<1, 1024, 0, stream>>>(bcur);
  k_bscat <<<sb, 256, 0, stream>>>(ei, bcur, pairs, E);
  k_bcscan<<<1, 1024, 0, stream>>>(bcur, boff, nb);
  k_bfin  <<<nb, 256, 0, stream>>>(pairs, bcur, boff, row_off, csr_src, N, E);

  // prep for MFMA gemms (pairs dead now; xb aliases it)
  k_tobf4 <<<(N * F_IN / 4 + 255) / 256, 256, 0, stream>>>((const float4*)x,
                                                           (ushort4*)xb, N * F_IN / 4);
  k_wpack3<<<160, 256, 0, stream>>>(W1, W2, W3, Wf1, Wf2, Wf3);

  int mb  = (N + 63) / 64;                // MFMA GEMM blocks (64 rows each)
  int nh2 = (N + 7) / 8;                  // half-wave-per-node agg

  // ---- layer 1
  k_mgemm<64, 8><<<mb, 256, 0, stream>>>((const short*)xb, (const short*)Wf1,
                                         as1, ad1, Hb, AS, AD, N);
  k_agg_post<4><<<nh2, 256, 0, stream>>>(Hb, row_off, csr_src, AS, AD, b1,
                                         nullptr, g1, be1, Fb0, N, 0);

  // ---- layer 2
  k_mgemm<128, 1><<<mb, 256, 0, stream>>>((const short*)Fb0, (const short*)Wf2,
                                          as2, ad2, Hb, AS, AD, N);
  k_agg_post<7><<<nh2, 256, 0, stream>>>(Hb, row_off, csr_src, AS, AD, b2,
                                         Fb0, g2, be2, Fb1, N, 1);

  // ---- layer 3
  k_mgemm<128, 1><<<mb, 256, 0, stream>>>((const short*)Fb1, (const short*)Wf3,
                                          as3, ad3, Hb, AS, AD, N);
  k_agg_post<7><<<nh2, 256, 0, stream>>>(Hb, row_off, csr_src, AS, AD, b3,
                                         Fb1, g3, be3, Fb2, N, 1);

  // ---- fused pool + MLP head
  k_head<<<G, 128, 0, stream>>>(Fb2, bat, lw1, lb1, lw2, lb2, (float*)d_out, N);
}

// Round 13
// 390.472 us; speedup vs baseline: 2.3290x; 1.0058x over previous
//
#include <hip/hip_runtime.h>
#include <hip/hip_bf16.h>
#include <cstdint>
#include <cstddef>

constexpr int F_IN = 64;
constexpr int HID  = 128;
constexpr int SCHUNK  = 4096;   // edges per scatter block (16/thread)
constexpr int BSTRIDE = 4096;   // pairs slots per bucket (mean ~1563 + >60 sigma)

typedef __attribute__((ext_vector_type(8))) short short8v;
typedef __attribute__((ext_vector_type(4))) float f32x4;

__device__ __forceinline__ float bf2f(unsigned short u) {
  return __uint_as_float((unsigned)u << 16);
}
__device__ __forceinline__ unsigned short f2bf(float x) {
  unsigned u = __float_as_uint(x);
  u += 0x7FFFu + ((u >> 16) & 1u);   // round-to-nearest-even
  return (unsigned short)(u >> 16);
}

// ================= CSR build: direct strided scatter, packed u32 pairs ======
// pair = s | (d&127)<<17   (s < 2^17 since N <= 131072; bucket = d>>7 implied)
__global__ __launch_bounds__(1024) void k_binit(int* __restrict__ bcur) {
  bcur[threadIdx.x] = threadIdx.x * BSTRIDE;
}

__global__ __launch_bounds__(256) void k_bscat(const int* __restrict__ ei,
                                               int* __restrict__ bcur,
                                               unsigned* __restrict__ pairs, int E) {
  __shared__ int lh[1024];
  __shared__ int lc[1024];
  int t = threadIdx.x;
  int start = blockIdx.x * SCHUNK;
  if (start >= E) return;
  int end = min(start + SCHUNK, E);
  for (int k = t; k < 1024; k += 256) { lh[k] = 0; lc[k] = 0; }
  __syncthreads();
  int dreg[SCHUNK / 256];
  #pragma unroll
  for (int q = 0; q < SCHUNK / 256; ++q) {
    int i = start + q * 256 + t;
    int d = (i < end) ? ei[E + i] : -1;
    dreg[q] = d;
    if (d >= 0) atomicAdd(&lh[d >> 7], 1);
  }
  __syncthreads();
  for (int k = t; k < 1024; k += 256) {
    int c = lh[k];
    lh[k] = (c > 0) ? atomicAdd(&bcur[k], c) : 0;
  }
  __syncthreads();
  #pragma unroll
  for (int q = 0; q < SCHUNK / 256; ++q) {
    int i = start + q * 256 + t;
    int d = dreg[q];
    if (d < 0) continue;
    unsigned s = (unsigned)ei[i];
    int b = d >> 7;
    int loc = atomicAdd(&lc[b], 1);
    pairs[lh[b] + loc] = s | ((unsigned)(d & 127) << 17);
  }
}

// single block: counts from final cursors -> exclusive scan -> boff
__global__ __launch_bounds__(1024) void k_bcscan(const int* __restrict__ bcur,
                                                 int* __restrict__ boff, int nb) {
  __shared__ int tmp[1024];
  int t = threadIdx.x;
  int v = (t < nb) ? (bcur[t] - t * BSTRIDE) : 0;
  tmp[t] = v;
  __syncthreads();
  #pragma unroll
  for (int off = 1; off < 1024; off <<= 1) {
    int x = tmp[t];
    int add = (t >= off) ? tmp[t - off] : 0;
    __syncthreads();
    tmp[t] = x + add;
    __syncthreads();
  }
  if (t < nb) {
    boff[t] = tmp[t] - v;
    if (t == nb - 1) boff[nb] = tmp[t];
  }
}

// block per bucket: self-loop first slot (deterministic) + pairs scatter.
__global__ __launch_bounds__(256) void k_bfin(const unsigned* __restrict__ pairs,
                                              const int* __restrict__ bcur,
                                              const int* __restrict__ boff,
                                              int* __restrict__ row_off,
                                              int* __restrict__ csr_src,
                                              int n, int E) {
  __shared__ int ldeg[128];
  __shared__ int lcur[128];
  int b = blockIdx.x;
  int t = threadIdx.x;
  int pb = b * BSTRIDE, pe = bcur[b];
  int fullbase = boff[b] + min(b << 7, n);
  int idx = (b << 7) + t;
  if (t < 128) ldeg[t] = (idx < n) ? 1 : 0;   // self-loop
  __syncthreads();
  for (int j = pb + t; j < pe; j += 256)
    atomicAdd(&ldeg[pairs[j] >> 17], 1);
  __syncthreads();
  int cnt = (t < 128) ? ldeg[t] : 0;
  for (int off = 1; off < 128; off <<= 1) {
    int add = (t < 128 && t >= off) ? ldeg[t - off] : 0;
    __syncthreads();
    if (t < 128) ldeg[t] += add;
    __syncthreads();
  }
  if (t < 128) {
    int base = fullbase + ldeg[t] - cnt;
    if (idx < n) {
      row_off[idx] = base;
      csr_src[base] = idx;        // self-loop first (deterministic slot)
      lcur[t] = base + 1;
    } else lcur[t] = base;
  }
  if (b == 0 && t == 255) row_off[n] = E + n;
  __syncthreads();
  for (int j = pb + t; j < pe; j += 256) {
    unsigned pr = pairs[j];
    int pos = atomicAdd(&lcur[pr >> 17], 1);
    csr_src[pos] = (int)(pr & 0x1FFFFu);
  }
}

// ---------------- fp32 -> bf16 convert (4-wide) ----------------
__global__ void k_tobf4(const float4* __restrict__ X, ushort4* __restrict__ Y,
                        int total4) {
  int i = blockIdx.x * 256 + threadIdx.x;
  if (i >= total4) return;
  float4 v = X[i];
  ushort4 o;
  o.x = f2bf(v.x); o.y = f2bf(v.y); o.z = f2bf(v.z); o.w = f2bf(v.w);
  Y[i] = o;
}

// ---- pack all three W into MFMA B-fragment order, bf16, one launch ----
__global__ void k_wpack3(const float* __restrict__ W1, const float* __restrict__ W2,
                         const float* __restrict__ W3, unsigned short* __restrict__ Wf1,
                         unsigned short* __restrict__ Wf2, unsigned short* __restrict__ Wf3) {
  int i = blockIdx.x * 256 + threadIdx.x;
  const float* W; unsigned short* Wf; int idx;
  if (i < 8192)       { W = W1; Wf = Wf1; idx = i; }
  else if (i < 24576) { W = W2; Wf = Wf2; idx = i - 8192; }
  else if (i < 40960) { W = W3; Wf = Wf3; idx = i - 24576; }
  else return;
  int j    = idx & 7;
  int lane = (idx >> 3) & 63;
  int t    = (idx >> 9) & 7;
  int ks   = idx >> 12;
  int k = ks * 32 + (lane >> 4) * 8 + j;
  int c = t * 16 + (lane & 15);
  Wf[idx] = f2bf(W[k * 128 + c]);
}

// ============ MFMA GEMM + fused alpha: [n,K] bf16 @ Wf -> Hb bf16, AS, AD ===
template<int K, int HEADS>
__global__ __launch_bounds__(256) void k_mgemm(const short* __restrict__ Xb,
                                               const short* __restrict__ Wf,
                                               const float* __restrict__ a_s,
                                               const float* __restrict__ a_d,
                                               unsigned short* __restrict__ Y,
                                               float* __restrict__ AS,
                                               float* __restrict__ AD, int n) {
  int wv   = threadIdx.x >> 6;
  int lane = threadIdx.x & 63;
  int r0   = blockIdx.x * 64 + wv * 16;
  int ln = lane & 15, kg = lane >> 4;
  f32x4 acc[8] = {};
  int arow = min(r0 + ln, n - 1);
  const short* aptr = Xb + arow * K + kg * 8;
  #pragma unroll
  for (int ks = 0; ks < K / 32; ++ks) {
    short8v a = *(const short8v*)(aptr + ks * 32);
    const short* wp = Wf + ks * 4096 + lane * 8;
    #pragma unroll
    for (int t = 0; t < 8; ++t) {
      short8v b = *(const short8v*)(wp + t * 512);
      acc[t] = __builtin_amdgcn_mfma_f32_16x16x32_bf16(a, b, acc[t], 0, 0, 0);
    }
  }
  float asv[8], adv[8];
  #pragma unroll
  for (int t = 0; t < 8; ++t) { asv[t] = a_s[t * 16 + ln]; adv[t] = a_d[t * 16 + ln]; }
  #pragma unroll
  for (int reg = 0; reg < 4; ++reg) {
    int r = r0 + kg * 4 + reg;
    bool valid = (r < n);
    if (HEADS == 1) {
      float s1 = 0.f, s2 = 0.f;
      #pragma unroll
      for (int t = 0; t < 8; ++t) {
        s1 = fmaf(acc[t][reg], asv[t], s1);
        s2 = fmaf(acc[t][reg], adv[t], s2);
      }
      #pragma unroll
      for (int off = 1; off < 16; off <<= 1) {
        s1 += __shfl_xor(s1, off);
        s2 += __shfl_xor(s2, off);
      }
      if (valid && ln == 0) { AS[r] = s1; AD[r] = s2; }
    } else {
      float s1[8], s2[8];
      #pragma unroll
      for (int t = 0; t < 8; ++t) {
        s1[t] = acc[t][reg] * asv[t];
        s2[t] = acc[t][reg] * adv[t];
      }
      #pragma unroll
      for (int off = 1; off < 16; off <<= 1) {
        #pragma unroll
        for (int t = 0; t < 8; ++t) {
          s1[t] += __shfl_xor(s1[t], off);
          s2[t] += __shfl_xor(s2[t], off);
        }
      }
      float w1 = s1[0], w2 = s2[0];
      #pragma unroll
      for (int t = 1; t < 8; ++t) {
        w1 = (ln == t) ? s1[t] : w1;
        w2 = (ln == t) ? s2[t] : w2;
      }
      if (valid && ln < 8) { AS[r * 8 + ln] = w1; AD[r * 8 + ln] = w2; }
    }
  }
  #pragma unroll
  for (int t = 0; t < 8; ++t) {
    #pragma unroll
    for (int reg = 0; reg < 4; ++reg) {
      int r = r0 + kg * 4 + reg;
      if (r < n) Y[r * 128 + t * 16 + ln] = f2bf(acc[t][reg]);
    }
  }
}

// ---- GAT aggregation: HALF-WAVE per dst, 4 ch/lane, cooperative no-max
// ---- softmax, deep load batching; + bias + ELU + LN + residual; bf16 I/O
template<int LOGC>
__global__ __launch_bounds__(256) void k_agg_post(const unsigned short* __restrict__ Hu,
    const int* __restrict__ row_off, const int* __restrict__ csr_src,
    const float* __restrict__ AS, const float* __restrict__ AD,
    const float* __restrict__ bias, const unsigned short* __restrict__ RES,
    const float* __restrict__ gamma, const float* __restrict__ beta,
    unsigned short* __restrict__ Yb, int n, int has_res) {
  int tid = blockIdx.x * 256 + threadIdx.x;
  int wid = tid >> 5;                      // half-wave (32 lanes) per node
  int ll  = threadIdx.x & 31;
  if (wid >= n) return;
  constexpr int NH  = HID >> LOGC;
  constexpr int SEG = (LOGC >= 7) ? 32 : (1 << (LOGC - 2));
  int abslane = threadIdx.x & 63;
  int c = ll << 2;
  int h = c >> LOGC;
  int r = ll & (SEG - 1);
  int sbase = abslane & ~(SEG - 1);
  float adv = AD[wid * NH + h];
  int jb = row_off[wid], je = row_off[wid + 1];
  float den = 0.f, a0 = 0.f, a1 = 0.f, a2 = 0.f, a3 = 0.f;
  for (int j0 = jb; j0 < je; j0 += SEG) {
    int cnt = min(SEG, je - j0);
    int s_l = 0; float p_l = 0.f;
    if (r < cnt) {
      s_l = csr_src[j0 + r];
      float e = AS[s_l * NH + h] + adv;
      e = (e > 0.f) ? e : 0.2f * e;
      p_l = __expf(e);
    }
    int k = 0;
    if (LOGC >= 7) {
      for (; k + 8 <= cnt; k += 8) {       // 8-deep: 8 loads in flight
        int   sk[8]; float pk[8]; ushort4 uu[8];
        #pragma unroll
        for (int q = 0; q < 8; ++q) sk[q] = __shfl(s_l, sbase | (k + q));
        #pragma unroll
        for (int q = 0; q < 8; ++q) uu[q] = *(const ushort4*)(Hu + (sk[q] << 7) + c);
        #pragma unroll
        for (int q = 0; q < 8; ++q) pk[q] = __shfl(p_l, sbase | (k + q));
        #pragma unroll
        for (int q = 0; q < 8; ++q) {
          den += pk[q];
          a0 = fmaf(pk[q], bf2f(uu[q].x), a0);
          a1 = fmaf(pk[q], bf2f(uu[q].y), a1);
          a2 = fmaf(pk[q], bf2f(uu[q].z), a2);
          a3 = fmaf(pk[q], bf2f(uu[q].w), a3);
        }
      }
    }
    for (; k + 4 <= cnt; k += 4) {
      int sk0 = __shfl(s_l, sbase | k);
      int sk1 = __shfl(s_l, sbase | (k + 1));
      int sk2 = __shfl(s_l, sbase | (k + 2));
      int sk3 = __shfl(s_l, sbase | (k + 3));
      ushort4 u0 = *(const ushort4*)(Hu + (sk0 << 7) + c);
      ushort4 u1 = *(const ushort4*)(Hu + (sk1 << 7) + c);
      ushort4 u2 = *(const ushort4*)(Hu + (sk2 << 7) + c);
      ushort4 u3 = *(const ushort4*)(Hu + (sk3 << 7) + c);
      float p0 = __shfl(p_l, sbase | k);
      float p1 = __shfl(p_l, sbase | (k + 1));
      float p2 = __shfl(p_l, sbase | (k + 2));
      float p3 = __shfl(p_l, sbase | (k + 3));
      den += (p0 + p1) + (p2 + p3);
      a0 = fmaf(p0, bf2f(u0.x), a0); a1 = fmaf(p0, bf2f(u0.y), a1);
      a2 = fmaf(p0, bf2f(u0.z), a2); a3 = fmaf(p0, bf2f(u0.w), a3);
      a0 = fmaf(p1, bf2f(u1.x), a0); a1 = fmaf(p1, bf2f(u1.y), a1);
      a2 = fmaf(p1, bf2f(u1.z), a2); a3 = fmaf(p1, bf2f(u1.w), a3);
      a0 = fmaf(p2, bf2f(u2.x), a0); a1 = fmaf(p2, bf2f(u2.y), a1);
      a2 = fmaf(p2, bf2f(u2.z), a2); a3 = fmaf(p2, bf2f(u2.w), a3);
      a0 = fmaf(p3, bf2f(u3.x), a0); a1 = fmaf(p3, bf2f(u3.y), a1);
      a2 = fmaf(p3, bf2f(u3.z), a2); a3 = fmaf(p3, bf2f(u3.w), a3);
    }
    for (; k < cnt; ++k) {
      int   s  = __shfl(s_l, sbase | k);
      float pk = __shfl(p_l, sbase | k);
      ushort4 u = *(const ushort4*)(Hu + (s << 7) + c);
      den += pk;
      a0 = fmaf(pk, bf2f(u.x), a0); a1 = fmaf(pk, bf2f(u.y), a1);
      a2 = fmaf(pk, bf2f(u.z), a2); a3 = fmaf(pk, bf2f(u.w), a3);
    }
  }
  float inv = 1.f / (den + 1e-16f);
  float4 bv = *(const float4*)(bias + c);
  float t0 = a0 * inv + bv.x;
  float t1 = a1 * inv + bv.y;
  float t2 = a2 * inv + bv.z;
  float t3 = a3 * inv + bv.w;
  float e0 = t0 > 0.f ? t0 : __expf(t0) - 1.f;
  float e1 = t1 > 0.f ? t1 : __expf(t1) - 1.f;
  float e2 = t2 > 0.f ? t2 : __expf(t2) - 1.f;
  float e3 = t3 > 0.f ? t3 : __expf(t3) - 1.f;
  float s1 = (e0 + e1) + (e2 + e3);
  float s2 = (e0 * e0 + e1 * e1) + (e2 * e2 + e3 * e3);
  #pragma unroll
  for (int off = 16; off >= 1; off >>= 1) {
    s1 += __shfl_xor(s1, off);
    s2 += __shfl_xor(s2, off);
  }
  float mu  = s1 * (1.f / 128.f);
  float var = s2 * (1.f / 128.f) - mu * mu;
  float rs  = rsqrtf(var + 1e-5f);
  int base = wid * HID;
  float r0 = 0.f, r1 = 0.f, r2 = 0.f, r3 = 0.f;
  if (has_res) {
    ushort4 rv = *(const ushort4*)(RES + base + c);
    r0 = bf2f(rv.x); r1 = bf2f(rv.y); r2 = bf2f(rv.z); r3 = bf2f(rv.w);
  }
  float4 gv = *(const float4*)(gamma + c);
  float4 betv = *(const float4*)(beta + c);
  ushort4 ob;
  ob.x = f2bf((e0 - mu) * rs * gv.x + betv.x + r0);
  ob.y = f2bf((e1 - mu) * rs * gv.y + betv.y + r1);
  ob.z = f2bf((e2 - mu) * rs * gv.z + betv.z + r2);
  ob.w = f2bf((e3 - mu) * rs * gv.w + betv.w + r3);
  *(ushort4*)(Yb + base + c) = ob;
}

// ---- fused head: block per graph: mean-pool -> MLP1+ELU -> MLP2 ----
__global__ __launch_bounds__(128) void k_head(const unsigned short* __restrict__ Hf,
    const int* __restrict__ batch, const float* __restrict__ lw1,
    const float* __restrict__ lb1, const float* __restrict__ lw2,
    const float* __restrict__ lb2, float* __restrict__ out, int n) {
  __shared__ float pooled[128];
  __shared__ float h1[128];
  int g = blockIdx.x;
  int c = threadIdx.x;
  int lo = 0, hi = n;
  while (lo < hi) { int mid = (lo + hi) >> 1; if (batch[mid] < g) lo = mid + 1; else hi = mid; }
  int start = lo;
  hi = n;
  while (lo < hi) { int mid = (lo + hi) >> 1; if (batch[mid] < g + 1) lo = mid + 1; else hi = mid; }
  int end = lo;
  float s = 0.f;
  for (int i = start; i < end; ++i) s += bf2f(Hf[(size_t)i * 128 + c]);
  pooled[c] = s / (float)max(end - start, 1);
  __syncthreads();
  float acc = lb1[c];
  #pragma unroll 8
  for (int k = 0; k < 128; ++k) acc = fmaf(pooled[k], lw1[k * 128 + c], acc);
  h1[c] = acc > 0.f ? acc : __expf(acc) - 1.f;
  __syncthreads();
  float acc2 = lb2[c];
  #pragma unroll 8
  for (int k = 0; k < 128; ++k) acc2 = fmaf(h1[k], lw2[k * 128 + c], acc2);
  out[(size_t)g * 128 + c] = acc2;
}

extern "C" void kernel_launch(void* const* d_in, const int* in_sizes, int n_in,
                              void* d_out, int out_size, void* d_ws, size_t ws_size,
                              hipStream_t stream) {
  const float* x   = (const float*)d_in[0];
  const int*   ei  = (const int*)d_in[1];
  const int*   bat = (const int*)d_in[2];
  const float* W1  = (const float*)d_in[3];
  const float* as1 = (const float*)d_in[4];
  const float* ad1 = (const float*)d_in[5];
  const float* b1  = (const float*)d_in[6];
  const float* W2  = (const float*)d_in[7];
  const float* as2 = (const float*)d_in[8];
  const float* ad2 = (const float*)d_in[9];
  const float* b2  = (const float*)d_in[10];
  const float* W3  = (const float*)d_in[11];
  const float* as3 = (const float*)d_in[12];
  const float* ad3 = (const float*)d_in[13];
  const float* b3  = (const float*)d_in[14];
  const float* g1  = (const float*)d_in[15];
  const float* be1 = (const float*)d_in[16];
  const float* g2  = (const float*)d_in[17];
  const float* be2 = (const float*)d_in[18];
  const float* g3  = (const float*)d_in[19];
  const float* be3 = (const float*)d_in[20];
  const float* lw1 = (const float*)d_in[21];
  const float* lb1 = (const float*)d_in[22];
  const float* lw2 = (const float*)d_in[23];
  const float* lb2 = (const float*)d_in[24];

  int N = in_sizes[0] / F_IN;
  int E = in_sizes[1] / 2;
  int G = out_size / HID;
  int tot = E + N;
  int nb  = (N + 127) >> 7;          // buckets (<=1024)

  char* p = (char*)d_ws;
  auto alloc = [&](size_t bytes) { char* r = p; p += (bytes + 511) & ~(size_t)511; return r; };
  int*      bcur    = (int*)     alloc(1024 * 4);
  int*      boff    = (int*)     alloc(1025 * 4);
  int*      row_off = (int*)     alloc((size_t)(N + 1) * 4);
  int*      csr_src = (int*)     alloc((size_t)tot * 4);
  unsigned* pairs   = (unsigned*)alloc((size_t)1024 * BSTRIDE * 4);  // dead after k_bfin
  float*    AS      = (float*)   alloc((size_t)N * 8 * 4);
  float*    AD      = (float*)   alloc((size_t)N * 8 * 4);
  unsigned short* Hb  = (unsigned short*)alloc((size_t)N * HID * 2);
  unsigned short* Fb0 = (unsigned short*)alloc((size_t)N * HID * 2);
  unsigned short* Fb1 = (unsigned short*)alloc((size_t)N * HID * 2);
  unsigned short* Fb2 = (unsigned short*)alloc((size_t)N * HID * 2);
  unsigned short* Wf1 = (unsigned short*)alloc(64 * 128 * 2);
  unsigned short* Wf2 = (unsigned short*)alloc(128 * 128 * 2);
  unsigned short* Wf3 = (unsigned short*)alloc(128 * 128 * 2);
  unsigned short* xb  = (unsigned short*)pairs;       // alias dead pairs buffer

  int sb = (E + SCHUNK - 1) / SCHUNK;
  k_binit <<<1, 1024, 0, stream>>>(bcur);
  k_bscat <<<sb, 256, 0, stream>>>(ei, bcur, pairs, E);
  k_bcscan<<<1, 1024, 0, stream>>>(bcur, boff, nb);
  k_bfin  <<<nb, 256, 0, stream>>>(pairs, bcur, boff, row_off, csr_src, N, E);

  // prep for MFMA gemms (pairs dead now; xb aliases it)
  k_tobf4 <<<(N * F_IN / 4 + 255) / 256, 256, 0, stream>>>((const float4*)x,
                                                           (ushort4*)xb, N * F_IN / 4);
  k_wpack3<<<160, 256, 0, stream>>>(W1, W2, W3, Wf1, Wf2, Wf3);

  int mb  = (N + 63) / 64;                // MFMA GEMM blocks (64 rows each)
  int nh2 = (N + 7) / 8;                  // half-wave-per-node agg

  // ---- layer 1
  k_mgemm<64, 8><<<mb, 256, 0, stream>>>((const short*)xb, (const short*)Wf1,
                                         as1, ad1, Hb, AS, AD, N);
  k_agg_post<4><<<nh2, 256, 0, stream>>>(Hb, row_off, csr_src, AS, AD, b1,
                                         nullptr, g1, be1, Fb0, N, 0);

  // ---- layer 2
  k_mgemm<128, 1><<<mb, 256, 0, stream>>>((const short*)Fb0, (const short*)Wf2,
                                          as2, ad2, Hb, AS, AD, N);
  k_agg_post<7><<<nh2, 256, 0, stream>>>(Hb, row_off, csr_src, AS, AD, b2,
                                         Fb0, g2, be2, Fb1, N, 1);

  // ---- layer 3
  k_mgemm<128, 1><<<mb, 256, 0, stream>>>((const short*)Fb1, (const short*)Wf3,
                                          as3, ad3, Hb, AS, AD, N);
  k_agg_post<7><<<nh2, 256, 0, stream>>>(Hb, row_off, csr_src, AS, AD, b3,
                                         Fb1, g3, be3, Fb2, N, 1);

  // ---- fused pool + MLP head
  k_head<<<G, 128, 0, stream>>>(Fb2, bat, lw1, lb1, lw2, lb2, (float*)d_out, N);
}